// Round 2
// baseline (791.170 us; speedup 1.0000x reference)
//
#include <hip/hip_runtime.h>

// TopoGraphBlock on MI355X — round 2: fp32, algebraically-decomposed edge MLPs.
//
// Key identity: concat(recv,send)@W1 = recv@W1[:F] + send@W1[F:], so edge-MLP
// layer 1 is per-NODE (cheap GEMMs); only layer 2 (128x128) stays per-EDGE.
// Per-edge FLOPs drop ~2x vs naive; total ~23 GFLOP fp32 (VALU-bound,
// no fp32 MFMA on CDNA4). Ideal @157 TF ~= 150-250 us.
//
// Round-2 deltas (no HW feedback yet — LDS-budget hazard fixes only):
//  - node_mlp: alias h1 onto Xs (64KB -> 32KB LDS, 2 -> 5 blocks/CU)
//  - reg_kernel: 32-row tiles (84KB -> ~43KB LDS)
//
// B=1024, NJ=24, NT=6, F=64, H=128, NODE_OUT=64, REG_OUT=4.
// Workspace: 6 node pre-act buffers + 3 pooled + Ac/Bc = ~96 MB floats.

#define DEVI __device__ __forceinline__

DEVI float4 f4z() { return make_float4(0.f, 0.f, 0.f, 0.f); }
DEVI float4 f4fma(float a, const float4 b, float4 c) {
    c.x = fmaf(a, b.x, c.x); c.y = fmaf(a, b.y, c.y);
    c.z = fmaf(a, b.z, c.z); c.w = fmaf(a, b.w, c.w);
    return c;
}
DEVI float4 f4add(float4 a, const float4 b) {
    a.x += b.x; a.y += b.y; a.z += b.z; a.w += b.w; return a;
}
DEVI float4 f4relu(float4 a) {
    a.x = fmaxf(a.x, 0.f); a.y = fmaxf(a.y, 0.f);
    a.z = fmaxf(a.z, 0.f); a.w = fmaxf(a.w, 0.f);
    return a;
}

// ---------------------------------------------------------------------------
// K1: batched per-node first-layer GEMM.  out(nr x 128) = X(nr x 64) @ W(64 x 128) [+ bias]
// Block: 32 rows x 128 cols, 256 threads, thread tile 4r x 4c. X,W staged in LDS.
// ---------------------------------------------------------------------------
struct PreCfg { const float* X; const float* W; const float* bias; float* out; int nrows; };
struct PreCfg6 { PreCfg c[6]; };

__global__ __launch_bounds__(256) void pre_gemm_kernel(PreCfg6 cfgs) {
    const PreCfg cfg = cfgs.c[blockIdx.y];
    if ((int)blockIdx.x * 32 >= cfg.nrows) return;
    __shared__ float Xs[32][64];
    __shared__ float Ws[64][128];
    const int tid = threadIdx.x;
    {   // stage X tile: 2048 floats
        const float4* s = (const float4*)(cfg.X + (size_t)blockIdx.x * 2048);
        float4* d = (float4*)&Xs[0][0];
        d[tid] = s[tid]; d[tid + 256] = s[tid + 256];
    }
    {   // stage W: 8192 floats
        const float4* s = (const float4*)cfg.W;
        float4* d = (float4*)&Ws[0][0];
        #pragma unroll
        for (int u = 0; u < 8; ++u) d[tid + u * 256] = s[tid + u * 256];
    }
    __syncthreads();
    const int cg = tid & 31, rg = tid >> 5;
    const int c0 = cg * 4, r0 = rg * 4;
    float4 acc[4] = {f4z(), f4z(), f4z(), f4z()};
    #pragma unroll 4
    for (int k = 0; k < 64; k += 4) {
        const float4 w0 = *(const float4*)&Ws[k + 0][c0];
        const float4 w1 = *(const float4*)&Ws[k + 1][c0];
        const float4 w2 = *(const float4*)&Ws[k + 2][c0];
        const float4 w3 = *(const float4*)&Ws[k + 3][c0];
        #pragma unroll
        for (int i = 0; i < 4; ++i) {
            const float4 x = *(const float4*)&Xs[r0 + i][k];
            acc[i] = f4fma(x.x, w0, acc[i]);
            acc[i] = f4fma(x.y, w1, acc[i]);
            acc[i] = f4fma(x.z, w2, acc[i]);
            acc[i] = f4fma(x.w, w3, acc[i]);
        }
    }
    const float4 bv = cfg.bias ? *(const float4*)(cfg.bias + c0) : f4z();
    #pragma unroll
    for (int i = 0; i < 4; ++i)
        *(float4*)&cfg.out[((size_t)blockIdx.x * 32 + r0 + i) * 128 + c0] = f4add(acc[i], bv);
}

// ---------------------------------------------------------------------------
// K2: edge second layer + masked mean.  One block per batch element b.
//   HV[e][k] = relu(A[r(e)][k] + B[s(e)][k])   (materialized per tile in LDS)
//   pooled[b][r][c] = inv * sum_s m[s] * relu(HV@W2 + b2)
// Tiles are r-aligned: ETILE=8*EPT edges, each thread's EPT consecutive edges
// share one r, so the segment-sum is thread-local (+small LDS reduce when
// multiple eg-groups share an r).  W2 streamed from L2 (wave-uniform address
// -> broadcast); HV GEMM reads are 2-address-per-wave LDS broadcasts.
// ---------------------------------------------------------------------------
template<int NR, int NS, int NSP, int EPT, bool MASKED>
__global__ __launch_bounds__(256) void edge_pool_kernel(
    const float* __restrict__ A, const float* __restrict__ Bp,
    const float* __restrict__ W2, const float* __restrict__ b2,
    const float* __restrict__ mask, float* __restrict__ pooled) {
    constexpr int ETILE = 8 * EPT;     // edges per tile (48 or 64)
    constexpr int RT    = ETILE / NSP; // recv rows per tile (2 or 8)
    constexpr int TILES = NR / RT;
    constexpr int EGR   = NSP / EPT;   // eg-groups per recv row (4 or 1)
    static_assert(EGR == 1 || RT == 2, "reduce path assumes RT==2");

    const int b = blockIdx.x, tid = threadIdx.x;
    __shared__ float As[NR][128];
    __shared__ float Bs[NSP][128];
    __shared__ float HV[ETILE][128];
    __shared__ float part[8][128];
    __shared__ float ms[NSP];

    {
        const float4* s = (const float4*)(A + (size_t)b * NR * 128);
        float4* d = (float4*)&As[0][0];
        for (int u = tid; u < NR * 32; u += 256) d[u] = s[u];
    }
    {
        const float4* s = (const float4*)(Bp + (size_t)b * NS * 128);
        float4* d = (float4*)&Bs[0][0];
        for (int u = tid; u < NSP * 32; u += 256) d[u] = (u < NS * 32) ? s[u] : f4z();
    }
    if (tid < NSP)
        ms[tid] = (tid < NS) ? (MASKED ? mask[b * 24 + tid] : 1.f) : 0.f;
    __syncthreads();

    float inv;
    if (MASKED) {
        float sm = 0.f;
        #pragma unroll
        for (int j = 0; j < NS; ++j) sm += ms[j];
        inv = 1.f / fmaxf(sm, 1.f);
    } else {
        inv = 1.f / (float)NS;
    }

    const int eg = tid >> 5, cg = tid & 31;
    const int c0 = cg * 4, e0 = eg * EPT;
    const float4 b2v = *(const float4*)(b2 + c0);

    for (int tile = 0; tile < TILES; ++tile) {
        const int rb = tile * RT;
        // materialize HV tile
        for (int u = tid; u < ETILE * 32; u += 256) {
            const int e = u >> 5, k4 = (u & 31) * 4;
            const int r = rb + e / NSP;
            const int s = e % NSP;
            const float4 a  = *(const float4*)&As[r][k4];
            const float4 bb = *(const float4*)&Bs[s][k4];
            *(float4*)&HV[e][k4] = f4relu(f4add(a, bb));
        }
        __syncthreads();
        // register-tiled GEMM: EPT edges x 4 cols, K=128
        float4 acc[EPT];
        #pragma unroll
        for (int i = 0; i < EPT; ++i) acc[i] = f4z();
        #pragma unroll 4
        for (int k = 0; k < 128; k += 4) {
            const float4 w0 = *(const float4*)(W2 + (size_t)(k + 0) * 128 + c0);
            const float4 w1 = *(const float4*)(W2 + (size_t)(k + 1) * 128 + c0);
            const float4 w2 = *(const float4*)(W2 + (size_t)(k + 2) * 128 + c0);
            const float4 w3 = *(const float4*)(W2 + (size_t)(k + 3) * 128 + c0);
            #pragma unroll
            for (int i = 0; i < EPT; ++i) {
                const float4 h = *(const float4*)&HV[e0 + i][k];
                acc[i] = f4fma(h.x, w0, acc[i]);
                acc[i] = f4fma(h.y, w1, acc[i]);
                acc[i] = f4fma(h.z, w2, acc[i]);
                acc[i] = f4fma(h.w, w3, acc[i]);
            }
        }
        // epilogue: bias, relu, mask-weight, thread-local segment sum
        float4 ps = f4z();
        #pragma unroll
        for (int i = 0; i < EPT; ++i) {
            const int s = (e0 + i) % NSP;
            const float m = ms[s];
            const float4 v = f4relu(f4add(acc[i], b2v));
            ps.x = fmaf(v.x, m, ps.x); ps.y = fmaf(v.y, m, ps.y);
            ps.z = fmaf(v.z, m, ps.z); ps.w = fmaf(v.w, m, ps.w);
        }
        if constexpr (EGR > 1) {
            *(float4*)&part[eg][c0] = ps;
            __syncthreads();
            {   // RT==2: 256 threads cover 2r x 128c
                const int rl = tid >> 7, c = tid & 127;
                float s2 = 0.f;
                #pragma unroll
                for (int g = 0; g < EGR; ++g) s2 += part[rl * EGR + g][c];
                pooled[((size_t)b * NR + rb + rl) * 128 + c] = s2 * inv;
            }
            __syncthreads();
        } else {
            *(float4*)&pooled[((size_t)b * NR + rb + eg) * 128 + c0] =
                make_float4(ps.x * inv, ps.y * inv, ps.z * inv, ps.w * inv);
            __syncthreads();
        }
    }
}

// ---------------------------------------------------------------------------
// K3/K4: fused node MLP2: out = relu(relu(concat(srcs)@W1+b1)@W2+b2) [*mask]
// Block: 64 rows, 256 threads. W1/W2 streamed from L2 (wave-uniform).
// smem aliases Xs (layer-1 input staging) and h1 (layer-1 output): Xs is dead
// once the last segment's GEMM finishes, and the loop-end __syncthreads
// separates the final Xs read from the h1 write. 32KB LDS -> 5 blocks/CU.
// ---------------------------------------------------------------------------
struct SrcSeg { const float* p; int w; };

template<int NSRC, bool MASKED>
__global__ __launch_bounds__(256) void node_mlp_kernel(
    SrcSeg s0, SrcSeg s1, SrcSeg s2,
    const float* __restrict__ W1, const float* __restrict__ b1,
    const float* __restrict__ W2, const float* __restrict__ b2,
    const float* __restrict__ mask, float* __restrict__ out) {
    __shared__ float smem[64 * 128];   // Xs during layer 1, h1 during layer 2
    const int tid = threadIdx.x;
    const size_t row0 = (size_t)blockIdx.x * 64;
    const int cg = tid & 31, rg = tid >> 5;
    const int c0 = cg * 4, r0 = rg * 8;

    float4 acc[8];
    #pragma unroll
    for (int i = 0; i < 8; ++i) acc[i] = f4z();

    const SrcSeg segs[3] = {s0, s1, s2};
    int kbase = 0;
    #pragma unroll
    for (int sI = 0; sI < NSRC; ++sI) {
        const int w = segs[sI].w;
        {
            const float4* s = (const float4*)(segs[sI].p + row0 * w);
            const int n4 = 64 * w / 4;
            float4* d = (float4*)smem;
            for (int u = tid; u < n4; u += 256) d[u] = s[u];
        }
        __syncthreads();
        for (int k = 0; k < w; k += 4) {
            const float4 w0 = *(const float4*)(W1 + (size_t)(kbase + k + 0) * 128 + c0);
            const float4 w1 = *(const float4*)(W1 + (size_t)(kbase + k + 1) * 128 + c0);
            const float4 w2 = *(const float4*)(W1 + (size_t)(kbase + k + 2) * 128 + c0);
            const float4 w3 = *(const float4*)(W1 + (size_t)(kbase + k + 3) * 128 + c0);
            #pragma unroll
            for (int i = 0; i < 8; ++i) {
                const float4 x = *(const float4*)&smem[(r0 + i) * w + k];
                acc[i] = f4fma(x.x, w0, acc[i]);
                acc[i] = f4fma(x.y, w1, acc[i]);
                acc[i] = f4fma(x.z, w2, acc[i]);
                acc[i] = f4fma(x.w, w3, acc[i]);
            }
        }
        kbase += w;
        __syncthreads();   // all Xs reads done -> safe to overwrite (next seg or h1)
    }
    const float4 b1v = *(const float4*)(b1 + c0);
    #pragma unroll
    for (int i = 0; i < 8; ++i)
        *(float4*)&smem[(r0 + i) * 128 + c0] = f4relu(f4add(acc[i], b1v));   // h1
    __syncthreads();

    // layer 2: N=64, thread tile 8r x 2c
    const int c0b = cg * 2;
    float2 a2[8];
    #pragma unroll
    for (int i = 0; i < 8; ++i) a2[i] = make_float2(0.f, 0.f);
    #pragma unroll 4
    for (int k = 0; k < 128; k += 4) {
        const float2 w0 = *(const float2*)(W2 + (size_t)(k + 0) * 64 + c0b);
        const float2 w1 = *(const float2*)(W2 + (size_t)(k + 1) * 64 + c0b);
        const float2 w2 = *(const float2*)(W2 + (size_t)(k + 2) * 64 + c0b);
        const float2 w3 = *(const float2*)(W2 + (size_t)(k + 3) * 64 + c0b);
        #pragma unroll
        for (int i = 0; i < 8; ++i) {
            const float4 h = *(const float4*)&smem[(r0 + i) * 128 + k];
            a2[i].x = fmaf(h.x, w0.x, fmaf(h.y, w1.x, fmaf(h.z, w2.x, fmaf(h.w, w3.x, a2[i].x))));
            a2[i].y = fmaf(h.x, w0.y, fmaf(h.y, w1.y, fmaf(h.z, w2.y, fmaf(h.w, w3.y, a2[i].y))));
        }
    }
    const float2 b2v = *(const float2*)(b2 + c0b);
    #pragma unroll
    for (int i = 0; i < 8; ++i) {
        const float m = MASKED ? mask[row0 + r0 + i] : 1.f;
        float2 v;
        v.x = fmaxf(a2[i].x + b2v.x, 0.f) * m;
        v.y = fmaxf(a2[i].y + b2v.y, 0.f) * m;
        *(float2*)&out[(row0 + r0 + i) * 64 + c0b] = v;
    }
}

// ---------------------------------------------------------------------------
// K5: classifier edges -> sigmoid score.  One block per b; 3 tiles of 48 edges.
// ---------------------------------------------------------------------------
__global__ __launch_bounds__(256) void cls_kernel(
    const float* __restrict__ Ac, const float* __restrict__ Bc,
    const float* __restrict__ Wc2, const float* __restrict__ bc2,
    const float* __restrict__ Wc3, const float* __restrict__ bc3,
    const float* __restrict__ mask, float* __restrict__ scores) {
    const int b = blockIdx.x, tid = threadIdx.x;
    __shared__ float As[6][128];
    __shared__ float Bs[24][128];
    __shared__ float HV[48][128];
    __shared__ float part[48][33];
    {
        const float4* s = (const float4*)(Ac + (size_t)b * 6 * 128);
        float4* d = (float4*)&As[0][0];
        if (tid < 192) d[tid] = s[tid];
    }
    {
        const float4* s = (const float4*)(Bc + (size_t)b * 24 * 128);
        float4* d = (float4*)&Bs[0][0];
        for (int u = tid; u < 768; u += 256) d[u] = s[u];
    }
    __syncthreads();
    const int eg = tid >> 5, cg = tid & 31;
    const int c0 = cg * 4, e0 = eg * 6;
    const float4 b2v = *(const float4*)(bc2 + c0);
    const float4 w3v = *(const float4*)(Wc3 + c0);
    const float bc3s = bc3[0];

    for (int tile = 0; tile < 3; ++tile) {
        const int rb = tile * 2;
        for (int u = tid; u < 1536; u += 256) {
            const int e = u >> 5, k4 = (u & 31) * 4;
            const int r = rb + (e >= 24);
            const int s = e - ((e >= 24) ? 24 : 0);
            const float4 a  = *(const float4*)&As[r][k4];
            const float4 bb = *(const float4*)&Bs[s][k4];
            *(float4*)&HV[e][k4] = f4relu(f4add(a, bb));
        }
        __syncthreads();
        float4 acc[6];
        #pragma unroll
        for (int i = 0; i < 6; ++i) acc[i] = f4z();
        #pragma unroll 4
        for (int k = 0; k < 128; k += 4) {
            const float4 w0 = *(const float4*)(Wc2 + (size_t)(k + 0) * 128 + c0);
            const float4 w1 = *(const float4*)(Wc2 + (size_t)(k + 1) * 128 + c0);
            const float4 w2 = *(const float4*)(Wc2 + (size_t)(k + 2) * 128 + c0);
            const float4 w3 = *(const float4*)(Wc2 + (size_t)(k + 3) * 128 + c0);
            #pragma unroll
            for (int i = 0; i < 6; ++i) {
                const float4 h = *(const float4*)&HV[e0 + i][k];
                acc[i] = f4fma(h.x, w0, acc[i]);
                acc[i] = f4fma(h.y, w1, acc[i]);
                acc[i] = f4fma(h.z, w2, acc[i]);
                acc[i] = f4fma(h.w, w3, acc[i]);
            }
        }
        #pragma unroll
        for (int i = 0; i < 6; ++i) {
            const float4 v = f4relu(f4add(acc[i], b2v));
            part[e0 + i][cg] = v.x * w3v.x + v.y * w3v.y + v.z * w3v.z + v.w * w3v.w;
        }
        __syncthreads();
        if (tid < 48) {
            float sum = 0.f;
            #pragma unroll
            for (int g = 0; g < 32; ++g) sum += part[tid][g];
            const float sig = 1.f / (1.f + expf(-(sum + bc3s)));
            const int t = rb + (tid >= 24);
            const int s = tid - ((tid >= 24) ? 24 : 0);
            scores[((size_t)b * 6 + t) * 24 + s] = sig * mask[b * 24 + s];
        }
        __syncthreads();
    }
}

// ---------------------------------------------------------------------------
// K6: per-top regression head: 64 -> 128 -> 128 -> 4, per-t weights.
// Grid (32 b-chunks of 32 rows, 6 t), block 256. ~43KB LDS.
// ---------------------------------------------------------------------------
__global__ __launch_bounds__(256) void reg_kernel(
    const float* __restrict__ tops_upd,
    const float* __restrict__ Wr1, const float* __restrict__ br1,
    const float* __restrict__ Wr2, const float* __restrict__ br2,
    const float* __restrict__ Wr3, const float* __restrict__ br3,
    float* __restrict__ outp) {
    const int t = blockIdx.y, bc = blockIdx.x, tid = threadIdx.x;
    __shared__ float Xs[32][64];
    __shared__ float h1[32][128];
    __shared__ float h2[32][132];
    __shared__ float W3s[512];
    for (int u = tid; u < 512; u += 256) {
        const int r = u >> 4, k4 = (u & 15) * 4;
        *(float4*)&Xs[r][k4] =
            *(const float4*)(tops_upd + ((size_t)(bc * 32 + r) * 6 + t) * 64 + k4);
    }
    for (int u = tid; u < 512; u += 256) W3s[u] = Wr3[t * 512 + u];
    __syncthreads();

    const int cg = tid & 31, rg = tid >> 5;
    const int c0 = cg * 4, r0 = rg * 4;
    const float* W1 = Wr1 + (size_t)t * 64 * 128;
    float4 acc[4];
    #pragma unroll
    for (int i = 0; i < 4; ++i) acc[i] = f4z();
    #pragma unroll 4
    for (int k = 0; k < 64; k += 4) {
        const float4 w0 = *(const float4*)(W1 + (size_t)(k + 0) * 128 + c0);
        const float4 w1 = *(const float4*)(W1 + (size_t)(k + 1) * 128 + c0);
        const float4 w2 = *(const float4*)(W1 + (size_t)(k + 2) * 128 + c0);
        const float4 w3 = *(const float4*)(W1 + (size_t)(k + 3) * 128 + c0);
        #pragma unroll
        for (int i = 0; i < 4; ++i) {
            const float4 x = *(const float4*)&Xs[r0 + i][k];
            acc[i] = f4fma(x.x, w0, acc[i]);
            acc[i] = f4fma(x.y, w1, acc[i]);
            acc[i] = f4fma(x.z, w2, acc[i]);
            acc[i] = f4fma(x.w, w3, acc[i]);
        }
    }
    const float4 b1v = *(const float4*)(br1 + t * 128 + c0);
    #pragma unroll
    for (int i = 0; i < 4; ++i)
        *(float4*)&h1[r0 + i][c0] = f4relu(f4add(acc[i], b1v));
    __syncthreads();

    const float* W2 = Wr2 + (size_t)t * 128 * 128;
    #pragma unroll
    for (int i = 0; i < 4; ++i) acc[i] = f4z();
    #pragma unroll 4
    for (int k = 0; k < 128; k += 4) {
        const float4 w0 = *(const float4*)(W2 + (size_t)(k + 0) * 128 + c0);
        const float4 w1 = *(const float4*)(W2 + (size_t)(k + 1) * 128 + c0);
        const float4 w2 = *(const float4*)(W2 + (size_t)(k + 2) * 128 + c0);
        const float4 w3 = *(const float4*)(W2 + (size_t)(k + 3) * 128 + c0);
        #pragma unroll
        for (int i = 0; i < 4; ++i) {
            const float4 h = *(const float4*)&h1[r0 + i][k];
            acc[i] = f4fma(h.x, w0, acc[i]);
            acc[i] = f4fma(h.y, w1, acc[i]);
            acc[i] = f4fma(h.z, w2, acc[i]);
            acc[i] = f4fma(h.w, w3, acc[i]);
        }
    }
    const float4 b2v = *(const float4*)(br2 + t * 128 + c0);
    #pragma unroll
    for (int i = 0; i < 4; ++i)
        *(float4*)&h2[r0 + i][c0] = f4relu(f4add(acc[i], b2v));
    __syncthreads();

    if (tid < 128) {   // final 128 -> 4: 32 rows x 4 cols
        const int r = tid >> 2, c = tid & 3;
        float a = 0.f;
        #pragma unroll 4
        for (int k = 0; k < 128; k += 4) {
            const float4 h = *(const float4*)&h2[r][k];
            a = fmaf(h.x, W3s[(k + 0) * 4 + c], a);
            a = fmaf(h.y, W3s[(k + 1) * 4 + c], a);
            a = fmaf(h.z, W3s[(k + 2) * 4 + c], a);
            a = fmaf(h.w, W3s[(k + 3) * 4 + c], a);
        }
        outp[((size_t)(bc * 32 + r) * 6 + t) * 4 + c] = a + br3[t * 4 + c];
    }
}

// ---------------------------------------------------------------------------
extern "C" void kernel_launch(void* const* d_in, const int* in_sizes, int n_in,
                              void* d_out, int out_size, void* d_ws, size_t ws_size,
                              hipStream_t stream) {
    const float* jets  = (const float*)d_in[0];
    const float* mask  = (const float*)d_in[1];
    const float* tops  = (const float*)d_in[2];
    const float* W_jj1 = (const float*)d_in[3];
    const float* b_jj1 = (const float*)d_in[4];
    const float* W_jj2 = (const float*)d_in[5];
    const float* b_jj2 = (const float*)d_in[6];
    const float* W_jt1 = (const float*)d_in[7];
    const float* b_jt1 = (const float*)d_in[8];
    const float* W_jt2 = (const float*)d_in[9];
    const float* b_jt2 = (const float*)d_in[10];
    const float* W_tj1 = (const float*)d_in[11];
    const float* b_tj1 = (const float*)d_in[12];
    const float* W_tj2 = (const float*)d_in[13];
    const float* b_tj2 = (const float*)d_in[14];
    const float* Wnj1  = (const float*)d_in[15];
    const float* bnj1  = (const float*)d_in[16];
    const float* Wnj2  = (const float*)d_in[17];
    const float* bnj2  = (const float*)d_in[18];
    const float* Wnt1  = (const float*)d_in[19];
    const float* bnt1  = (const float*)d_in[20];
    const float* Wnt2  = (const float*)d_in[21];
    const float* bnt2  = (const float*)d_in[22];
    const float* Wc1   = (const float*)d_in[23];
    const float* bc1   = (const float*)d_in[24];
    const float* Wc2   = (const float*)d_in[25];
    const float* bc2   = (const float*)d_in[26];
    const float* Wc3   = (const float*)d_in[27];
    const float* bc3   = (const float*)d_in[28];
    const float* Wr1   = (const float*)d_in[29];
    const float* br1   = (const float*)d_in[30];
    const float* Wr2   = (const float*)d_in[31];
    const float* br2   = (const float*)d_in[32];
    const float* Wr3   = (const float*)d_in[33];
    const float* br3   = (const float*)d_in[34];

    float* ws = (float*)d_ws;
    constexpr size_t SZ_J = (size_t)1024 * 24 * 128; // 3,145,728
    constexpr size_t SZ_T = (size_t)1024 * 6 * 128;  //   786,432
    float* Ajj = ws;
    float* Bjj = Ajj + SZ_J;
    float* Ajt = Bjj + SZ_J;
    float* Btj = Ajt + SZ_J;
    float* Atj = Btj + SZ_J;
    float* Bjt = Atj + SZ_T;
    float* Pjj = Bjt + SZ_T;
    float* Pjt = Pjj + SZ_J;
    float* Ptj = Pjt + SZ_J;
    float* Acc = Ptj + SZ_T;
    float* Bcc = Acc + SZ_T;   // total 25,165,824 floats (~96 MB)

    float* outp     = (float*)d_out;
    float* upd_jets = outp;
    float* upd_tops = outp + (size_t)1024 * 24 * 64;
    float* scores   = upd_tops + (size_t)1024 * 6 * 64;
    float* regr     = scores + (size_t)1024 * 6 * 24;

    {   // per-node first-layer pre-activations for the 3 edge MLPs
        // concat(recv,send)@W1 = recv@W1[:64] + send@W1[64:]
        PreCfg6 cfg;
        cfg.c[0] = {jets, W_jj1,            b_jj1,  Ajj, 24576};
        cfg.c[1] = {jets, W_jj1 + 64 * 128, nullptr, Bjj, 24576};
        cfg.c[2] = {jets, W_jt1,            b_jt1,  Ajt, 24576};
        cfg.c[3] = {jets, W_tj1 + 64 * 128, nullptr, Btj, 24576};
        cfg.c[4] = {tops, W_tj1,            b_tj1,  Atj, 6144};
        cfg.c[5] = {tops, W_jt1 + 64 * 128, nullptr, Bjt, 6144};
        pre_gemm_kernel<<<dim3(768, 6), 256, 0, stream>>>(cfg);
    }
    edge_pool_kernel<24, 24, 24, 6, true ><<<1024, 256, 0, stream>>>(Ajj, Bjj, W_jj2, b_jj2, mask, Pjj);
    edge_pool_kernel<24,  6,  8, 8, false><<<1024, 256, 0, stream>>>(Ajt, Bjt, W_jt2, b_jt2, nullptr, Pjt);
    edge_pool_kernel< 6, 24, 24, 6, true ><<<1024, 256, 0, stream>>>(Atj, Btj, W_tj2, b_tj2, mask, Ptj);

    node_mlp_kernel<3, true ><<<384, 256, 0, stream>>>(
        SrcSeg{jets, 64}, SrcSeg{Pjj, 128}, SrcSeg{Pjt, 128},
        Wnj1, bnj1, Wnj2, bnj2, mask, upd_jets);
    node_mlp_kernel<2, false><<<96, 256, 0, stream>>>(
        SrcSeg{tops, 64}, SrcSeg{Ptj, 128}, SrcSeg{nullptr, 0},
        Wnt1, bnt1, Wnt2, bnt2, nullptr, upd_tops);

    {   // classifier-edge first layer pre-activations
        PreCfg6 cfg;
        cfg.c[0] = {upd_jets, Wc1 + 64 * 128, nullptr, Bcc, 24576};
        cfg.c[1] = {upd_tops, Wc1,            bc1,     Acc, 6144};
        for (int i = 2; i < 6; ++i) cfg.c[i] = {nullptr, nullptr, nullptr, nullptr, 0};
        pre_gemm_kernel<<<dim3(768, 2), 256, 0, stream>>>(cfg);
    }
    cls_kernel<<<1024, 256, 0, stream>>>(Acc, Bcc, Wc2, bc2, Wc3, bc3, mask, scores);
    reg_kernel<<<dim3(32, 6), 256, 0, stream>>>(upd_tops, Wr1, br1, Wr2, br2, Wr3, br3, regr);
}

// Round 3
// 426.686 us; speedup vs baseline: 1.8542x; 1.8542x over previous
//
#include <hip/hip_runtime.h>
#include <hip/hip_bf16.h>

// TopoGraphBlock on MI355X — round 3: split-bf16 MFMA edge GEMMs.
//
// Round-2 evidence: edge_pool(jj) = 301us, VALUBusy 62%, Occupancy 26%,
// MfmaUtil 0 — fp32-VALU-bound at 41% of the 157TF vector peak, with each
// wave re-streaming 64KB of W2 from L2 per tile (~6.3GB total).
// Round-3: move the per-edge 128x128 layer-2 GEMMs (jj/jt/tj/cls ~ 34 GFLOP
// logical) onto the 2075-TF bf16 MFMA pipe using a hi/lo split:
//   A*B ~= Ah*Bh + Al*Bh + Ah*Bl,  Al = bf16(A - Ah)  (rel err ~2^-17,
// fp32-grade; predicted absmax stays ~0.016). W2 is pre-split into per-lane
// B-fragments held in REGISTERS (read once per block), HV tiles materialized
// as hi/lo bf16 in LDS. 48-edge groups = 3 MFMA M-tiles, no padding waste.
//
// MFMA 16x16x32 bf16 layouts (learn_hip m89-verified D; k-contig A/B frags):
//   A: lane holds A[row=lane&15][k=(lane>>4)*8 .. +7]
//   B: lane holds B[k=(lane>>4)*8 .. +7][col=lane&15]
//   D: lane reg j holds D[row=(lane>>4)*4+j][col=lane&15]

#define DEVI __device__ __forceinline__

typedef __attribute__((ext_vector_type(4))) float  floatx4;
typedef __attribute__((ext_vector_type(8))) __bf16 bf16x8;
typedef __attribute__((ext_vector_type(4))) __bf16 bf16x4;

DEVI float4 f4z() { return make_float4(0.f, 0.f, 0.f, 0.f); }
DEVI float4 f4fma(float a, const float4 b, float4 c) {
    c.x = fmaf(a, b.x, c.x); c.y = fmaf(a, b.y, c.y);
    c.z = fmaf(a, b.z, c.z); c.w = fmaf(a, b.w, c.w);
    return c;
}
DEVI float4 f4add(float4 a, const float4 b) {
    a.x += b.x; a.y += b.y; a.z += b.z; a.w += b.w; return a;
}
DEVI float4 f4relu(float4 a) {
    a.x = fmaxf(a.x, 0.f); a.y = fmaxf(a.y, 0.f);
    a.z = fmaxf(a.z, 0.f); a.w = fmaxf(a.w, 0.f);
    return a;
}
DEVI floatx4 mfma_bf16(bf16x8 a, bf16x8 b, floatx4 c) {
    return __builtin_amdgcn_mfma_f32_16x16x32_bf16(a, b, c, 0, 0, 0);
}

// ---------------------------------------------------------------------------
// K1: batched per-node first-layer GEMM.  out(nr x 128) = X(nr x 64) @ W(64 x 128) [+ bias]
// ---------------------------------------------------------------------------
struct PreCfg { const float* X; const float* W; const float* bias; float* out; int nrows; };
struct PreCfg6 { PreCfg c[6]; };

__global__ __launch_bounds__(256) void pre_gemm_kernel(PreCfg6 cfgs) {
    const PreCfg cfg = cfgs.c[blockIdx.y];
    if ((int)blockIdx.x * 32 >= cfg.nrows) return;
    __shared__ float Xs[32][64];
    __shared__ float Ws[64][128];
    const int tid = threadIdx.x;
    {
        const float4* s = (const float4*)(cfg.X + (size_t)blockIdx.x * 2048);
        float4* d = (float4*)&Xs[0][0];
        d[tid] = s[tid]; d[tid + 256] = s[tid + 256];
    }
    {
        const float4* s = (const float4*)cfg.W;
        float4* d = (float4*)&Ws[0][0];
        #pragma unroll
        for (int u = 0; u < 8; ++u) d[tid + u * 256] = s[tid + u * 256];
    }
    __syncthreads();
    const int cg = tid & 31, rg = tid >> 5;
    const int c0 = cg * 4, r0 = rg * 4;
    float4 acc[4] = {f4z(), f4z(), f4z(), f4z()};
    #pragma unroll 4
    for (int k = 0; k < 64; k += 4) {
        const float4 w0 = *(const float4*)&Ws[k + 0][c0];
        const float4 w1 = *(const float4*)&Ws[k + 1][c0];
        const float4 w2 = *(const float4*)&Ws[k + 2][c0];
        const float4 w3 = *(const float4*)&Ws[k + 3][c0];
        #pragma unroll
        for (int i = 0; i < 4; ++i) {
            const float4 x = *(const float4*)&Xs[r0 + i][k];
            acc[i] = f4fma(x.x, w0, acc[i]);
            acc[i] = f4fma(x.y, w1, acc[i]);
            acc[i] = f4fma(x.z, w2, acc[i]);
            acc[i] = f4fma(x.w, w3, acc[i]);
        }
    }
    const float4 bv = cfg.bias ? *(const float4*)(cfg.bias + c0) : f4z();
    #pragma unroll
    for (int i = 0; i < 4; ++i)
        *(float4*)&cfg.out[((size_t)blockIdx.x * 32 + r0 + i) * 128 + c0] = f4add(acc[i], bv);
}

// ---------------------------------------------------------------------------
// K2 (NEW): edge layer-2 GEMM on MFMA, split-bf16, fused pooling epilogue.
// One block per batch element b; 512 threads = 8 waves = 8 column-tiles.
// EPI: 0 = register pooling (RPG==2: jj, tj), 1 = LDS segment reduce (jt),
//      2 = classifier score (dot Wc3 + sigmoid * mask).
// ---------------------------------------------------------------------------
template<int NR, int NS, int EPI, bool MASKED>
__global__ __launch_bounds__(512) void edge_mfma_kernel(
    const float* __restrict__ A, const float* __restrict__ Bp,
    const float* __restrict__ W2, const float* __restrict__ b2,
    const float* __restrict__ mask,
    const float* __restrict__ Wc3, const float* __restrict__ bc3,
    float* __restrict__ out)
{
    constexpr int NE    = NR * NS;
    constexpr int NG    = NE / 48;        // 48-edge groups (jj:12, others:3)
    constexpr int RPG   = 48 / NS;        // recv rows per group (2 or 8)
    constexpr int PITCH = 136;            // HV row pitch in bf16 (2-way banks)
    constexpr int OP    = 132;            // POUT row pitch in f32
    constexpr int POUT_SZ = (EPI == 0) ? 4 : 48 * OP;
    constexpr int PART_SZ = (EPI == 2) ? 48 * 9 : 4;

    __shared__ __bf16 HVh[48 * PITCH];
    __shared__ __bf16 HVl[48 * PITCH];
    __shared__ float  msh[32];
    __shared__ float  POUT[POUT_SZ];
    __shared__ float  part[PART_SZ];

    const int b    = blockIdx.x;
    const int tid  = threadIdx.x;
    const int lane = tid & 63;
    const int wave = tid >> 6;            // == column tile 0..7
    const int lhi  = lane >> 4;           // k-group (A/B), row-group (D)
    const int llo  = lane & 15;           // A-row / B-col / D-col
    const int c    = wave * 16 + llo;     // output column 0..127

    if (tid < 32) msh[tid] = (tid < NS) ? (MASKED ? mask[b * 24 + tid] : 1.f) : 0.f;

    // W2 -> per-lane split B-fragments (registers), once per block.
    bf16x8 bh[4], bl[4];
    {
        const float* w2c = W2 + c;
        #pragma unroll
        for (int kc = 0; kc < 4; ++kc) {
            #pragma unroll
            for (int j = 0; j < 8; ++j) {
                const float w = w2c[(size_t)(kc * 32 + lhi * 8 + j) * 128];
                const __bf16 h = (__bf16)w;
                bh[kc][j] = h;
                bl[kc][j] = (__bf16)(w - (float)h);
            }
        }
    }
    const float b2c = b2[c];
    __syncthreads();

    float inv = 1.f;
    if constexpr (EPI != 2) {
        if constexpr (MASKED) {
            float sm = 0.f;
            #pragma unroll
            for (int s = 0; s < NS; ++s) sm += msh[s];
            inv = 1.f / fmaxf(sm, 1.f);
        } else {
            inv = 1.f / (float)NS;
        }
    }

    for (int g = 0; g < NG; ++g) {
        // ---- materialize hi/lo HV for 48 edges x 128 k into LDS ----
        #pragma unroll
        for (int it = 0; it < 3; ++it) {
            const int u = tid + it * 512;               // 1536 float4-chunks
            const int e = u >> 5, kq = u & 31;
            const int r = g * RPG + e / NS;
            const int s = e % NS;
            const float4 a4 = *(const float4*)(A  + ((size_t)b * NR + r) * 128 + kq * 4);
            const float4 p4 = *(const float4*)(Bp + ((size_t)b * NS + s) * 128 + kq * 4);
            const float v[4] = {fmaxf(a4.x + p4.x, 0.f), fmaxf(a4.y + p4.y, 0.f),
                                fmaxf(a4.z + p4.z, 0.f), fmaxf(a4.w + p4.w, 0.f)};
            bf16x4 hh, hl;
            #pragma unroll
            for (int q = 0; q < 4; ++q) {
                const __bf16 h = (__bf16)v[q];
                hh[q] = h;
                hl[q] = (__bf16)(v[q] - (float)h);
            }
            *(bf16x4*)&HVh[e * PITCH + kq * 4] = hh;
            *(bf16x4*)&HVl[e * PITCH + kq * 4] = hl;
        }
        __syncthreads();

        // ---- 3 M-tiles of 16 edges; 12 split-MFMAs each ----
        floatx4 accs[3];
        #pragma unroll
        for (int mt = 0; mt < 3; ++mt) {
            const int row = mt * 16 + llo;
            bf16x8 ah[4], al[4];
            #pragma unroll
            for (int kc = 0; kc < 4; ++kc) {
                ah[kc] = *(const bf16x8*)&HVh[row * PITCH + kc * 32 + lhi * 8];
                al[kc] = *(const bf16x8*)&HVl[row * PITCH + kc * 32 + lhi * 8];
            }
            floatx4 acc = {0.f, 0.f, 0.f, 0.f};
            #pragma unroll
            for (int kc = 0; kc < 4; ++kc) {
                acc = mfma_bf16(ah[kc], bh[kc], acc);
                acc = mfma_bf16(al[kc], bh[kc], acc);
                acc = mfma_bf16(ah[kc], bl[kc], acc);
            }
            accs[mt] = acc;
        }

        if constexpr (EPI == 0) {
            // register pooling over the 2 recv rows of this group
            float p0 = 0.f, p1 = 0.f;
            #pragma unroll
            for (int mt = 0; mt < 3; ++mt) {
                #pragma unroll
                for (int j = 0; j < 4; ++j) {
                    const int el = mt * 16 + lhi * 4 + j;       // D row = edge
                    const int s  = (el >= NS) ? el - NS : el;
                    const float v = fmaxf(accs[mt][j] + b2c, 0.f) * msh[s];
                    if (el >= NS) p1 += v; else p0 += v;
                }
            }
            p0 += __shfl_xor(p0, 16); p0 += __shfl_xor(p0, 32);
            p1 += __shfl_xor(p1, 16); p1 += __shfl_xor(p1, 32);
            if (lhi == 0) {
                out[((size_t)b * NR + g * 2 + 0) * 128 + c] = p0 * inv;
                out[((size_t)b * NR + g * 2 + 1) * 128 + c] = p1 * inv;
            }
            __syncthreads();
        } else if constexpr (EPI == 1) {
            #pragma unroll
            for (int mt = 0; mt < 3; ++mt) {
                #pragma unroll
                for (int j = 0; j < 4; ++j) {
                    const int el = mt * 16 + lhi * 4 + j;
                    const int s  = el % NS;
                    POUT[el * OP + c] = fmaxf(accs[mt][j] + b2c, 0.f) * msh[s];
                }
            }
            __syncthreads();
            for (int u = tid; u < RPG * 128; u += 512) {
                const int rl = u >> 7, cc = u & 127;
                float sm2 = 0.f;
                #pragma unroll
                for (int ss = 0; ss < NS; ++ss) sm2 += POUT[(rl * NS + ss) * OP + cc];
                out[((size_t)b * NR + g * RPG + rl) * 128 + cc] = sm2 * inv;
            }
            __syncthreads();
        } else {
            // classifier: relu out -> dot Wc3 -> sigmoid -> * mask[s]
            #pragma unroll
            for (int mt = 0; mt < 3; ++mt) {
                #pragma unroll
                for (int j = 0; j < 4; ++j) {
                    const int el = mt * 16 + lhi * 4 + j;
                    POUT[el * OP + c] = fmaxf(accs[mt][j] + b2c, 0.f);
                }
            }
            __syncthreads();
            if (tid < 384) {
                const int e = tid >> 3, cq = tid & 7;
                float sp = 0.f;
                #pragma unroll
                for (int i = 0; i < 16; ++i)
                    sp += POUT[e * OP + cq * 16 + i] * Wc3[cq * 16 + i];
                part[e * 9 + cq] = sp;
            }
            __syncthreads();
            if (tid < 48) {
                float sm2 = 0.f;
                #pragma unroll
                for (int q = 0; q < 8; ++q) sm2 += part[tid * 9 + q];
                const int rr = g * 2 + (tid >= 24 ? 1 : 0);
                const int ss = (tid >= 24) ? tid - 24 : tid;
                out[((size_t)b * NR + rr) * NS + ss] =
                    msh[ss] / (1.f + expf(-(sm2 + bc3[0])));
            }
            __syncthreads();
        }
    }
}

// ---------------------------------------------------------------------------
// K3/K4: fused node MLP2 (fp32): out = relu(relu(concat(srcs)@W1+b1)@W2+b2) [*mask]
// ---------------------------------------------------------------------------
struct SrcSeg { const float* p; int w; };

template<int NSRC, bool MASKED>
__global__ __launch_bounds__(256) void node_mlp_kernel(
    SrcSeg s0, SrcSeg s1, SrcSeg s2,
    const float* __restrict__ W1, const float* __restrict__ b1,
    const float* __restrict__ W2, const float* __restrict__ b2,
    const float* __restrict__ mask, float* __restrict__ out) {
    __shared__ float smem[64 * 128];   // Xs during layer 1, h1 during layer 2
    const int tid = threadIdx.x;
    const size_t row0 = (size_t)blockIdx.x * 64;
    const int cg = tid & 31, rg = tid >> 5;
    const int c0 = cg * 4, r0 = rg * 8;

    float4 acc[8];
    #pragma unroll
    for (int i = 0; i < 8; ++i) acc[i] = f4z();

    const SrcSeg segs[3] = {s0, s1, s2};
    int kbase = 0;
    #pragma unroll
    for (int sI = 0; sI < NSRC; ++sI) {
        const int w = segs[sI].w;
        {
            const float4* s = (const float4*)(segs[sI].p + row0 * w);
            const int n4 = 64 * w / 4;
            float4* d = (float4*)smem;
            for (int u = tid; u < n4; u += 256) d[u] = s[u];
        }
        __syncthreads();
        for (int k = 0; k < w; k += 4) {
            const float4 w0 = *(const float4*)(W1 + (size_t)(kbase + k + 0) * 128 + c0);
            const float4 w1 = *(const float4*)(W1 + (size_t)(kbase + k + 1) * 128 + c0);
            const float4 w2 = *(const float4*)(W1 + (size_t)(kbase + k + 2) * 128 + c0);
            const float4 w3 = *(const float4*)(W1 + (size_t)(kbase + k + 3) * 128 + c0);
            #pragma unroll
            for (int i = 0; i < 8; ++i) {
                const float4 x = *(const float4*)&smem[(r0 + i) * w + k];
                acc[i] = f4fma(x.x, w0, acc[i]);
                acc[i] = f4fma(x.y, w1, acc[i]);
                acc[i] = f4fma(x.z, w2, acc[i]);
                acc[i] = f4fma(x.w, w3, acc[i]);
            }
        }
        kbase += w;
        __syncthreads();
    }
    const float4 b1v = *(const float4*)(b1 + c0);
    #pragma unroll
    for (int i = 0; i < 8; ++i)
        *(float4*)&smem[(r0 + i) * 128 + c0] = f4relu(f4add(acc[i], b1v));
    __syncthreads();

    const int c0b = cg * 2;
    float2 a2[8];
    #pragma unroll
    for (int i = 0; i < 8; ++i) a2[i] = make_float2(0.f, 0.f);
    #pragma unroll 4
    for (int k = 0; k < 128; k += 4) {
        const float2 w0 = *(const float2*)(W2 + (size_t)(k + 0) * 64 + c0b);
        const float2 w1 = *(const float2*)(W2 + (size_t)(k + 1) * 64 + c0b);
        const float2 w2 = *(const float2*)(W2 + (size_t)(k + 2) * 64 + c0b);
        const float2 w3 = *(const float2*)(W2 + (size_t)(k + 3) * 64 + c0b);
        #pragma unroll
        for (int i = 0; i < 8; ++i) {
            const float4 h = *(const float4*)&smem[(r0 + i) * 128 + k];
            a2[i].x = fmaf(h.x, w0.x, fmaf(h.y, w1.x, fmaf(h.z, w2.x, fmaf(h.w, w3.x, a2[i].x))));
            a2[i].y = fmaf(h.x, w0.y, fmaf(h.y, w1.y, fmaf(h.z, w2.y, fmaf(h.w, w3.y, a2[i].y))));
        }
    }
    const float2 b2v = *(const float2*)(b2 + c0b);
    #pragma unroll
    for (int i = 0; i < 8; ++i) {
        const float m = MASKED ? mask[row0 + r0 + i] : 1.f;
        float2 v;
        v.x = fmaxf(a2[i].x + b2v.x, 0.f) * m;
        v.y = fmaxf(a2[i].y + b2v.y, 0.f) * m;
        *(float2*)&out[(row0 + r0 + i) * 64 + c0b] = v;
    }
}

// ---------------------------------------------------------------------------
// K6: per-top regression head (fp32): 64 -> 128 -> 128 -> 4, per-t weights.
// ---------------------------------------------------------------------------
__global__ __launch_bounds__(256) void reg_kernel(
    const float* __restrict__ tops_upd,
    const float* __restrict__ Wr1, const float* __restrict__ br1,
    const float* __restrict__ Wr2, const float* __restrict__ br2,
    const float* __restrict__ Wr3, const float* __restrict__ br3,
    float* __restrict__ outp) {
    const int t = blockIdx.y, bc = blockIdx.x, tid = threadIdx.x;
    __shared__ float Xs[32][64];
    __shared__ float h1[32][128];
    __shared__ float h2[32][132];
    __shared__ float W3s[512];
    for (int u = tid; u < 512; u += 256) {
        const int r = u >> 4, k4 = (u & 15) * 4;
        *(float4*)&Xs[r][k4] =
            *(const float4*)(tops_upd + ((size_t)(bc * 32 + r) * 6 + t) * 64 + k4);
    }
    for (int u = tid; u < 512; u += 256) W3s[u] = Wr3[t * 512 + u];
    __syncthreads();

    const int cg = tid & 31, rg = tid >> 5;
    const int c0 = cg * 4, r0 = rg * 4;
    const float* W1 = Wr1 + (size_t)t * 64 * 128;
    float4 acc[4];
    #pragma unroll
    for (int i = 0; i < 4; ++i) acc[i] = f4z();
    #pragma unroll 4
    for (int k = 0; k < 64; k += 4) {
        const float4 w0 = *(const float4*)(W1 + (size_t)(k + 0) * 128 + c0);
        const float4 w1 = *(const float4*)(W1 + (size_t)(k + 1) * 128 + c0);
        const float4 w2 = *(const float4*)(W1 + (size_t)(k + 2) * 128 + c0);
        const float4 w3 = *(const float4*)(W1 + (size_t)(k + 3) * 128 + c0);
        #pragma unroll
        for (int i = 0; i < 4; ++i) {
            const float4 x = *(const float4*)&Xs[r0 + i][k];
            acc[i] = f4fma(x.x, w0, acc[i]);
            acc[i] = f4fma(x.y, w1, acc[i]);
            acc[i] = f4fma(x.z, w2, acc[i]);
            acc[i] = f4fma(x.w, w3, acc[i]);
        }
    }
    const float4 b1v = *(const float4*)(br1 + t * 128 + c0);
    #pragma unroll
    for (int i = 0; i < 4; ++i)
        *(float4*)&h1[r0 + i][c0] = f4relu(f4add(acc[i], b1v));
    __syncthreads();

    const float* W2 = Wr2 + (size_t)t * 128 * 128;
    #pragma unroll
    for (int i = 0; i < 4; ++i) acc[i] = f4z();
    #pragma unroll 4
    for (int k = 0; k < 128; k += 4) {
        const float4 w0 = *(const float4*)(W2 + (size_t)(k + 0) * 128 + c0);
        const float4 w1 = *(const float4*)(W2 + (size_t)(k + 1) * 128 + c0);
        const float4 w2 = *(const float4*)(W2 + (size_t)(k + 2) * 128 + c0);
        const float4 w3 = *(const float4*)(W2 + (size_t)(k + 3) * 128 + c0);
        #pragma unroll
        for (int i = 0; i < 4; ++i) {
            const float4 h = *(const float4*)&h1[r0 + i][k];
            acc[i] = f4fma(h.x, w0, acc[i]);
            acc[i] = f4fma(h.y, w1, acc[i]);
            acc[i] = f4fma(h.z, w2, acc[i]);
            acc[i] = f4fma(h.w, w3, acc[i]);
        }
    }
    const float4 b2v = *(const float4*)(br2 + t * 128 + c0);
    #pragma unroll
    for (int i = 0; i < 4; ++i)
        *(float4*)&h2[r0 + i][c0] = f4relu(f4add(acc[i], b2v));
    __syncthreads();

    if (tid < 128) {
        const int r = tid >> 2, cc = tid & 3;
        float a = 0.f;
        #pragma unroll 4
        for (int k = 0; k < 128; k += 4) {
            const float4 h = *(const float4*)&h2[r][k];
            a = fmaf(h.x, W3s[(k + 0) * 4 + cc], a);
            a = fmaf(h.y, W3s[(k + 1) * 4 + cc], a);
            a = fmaf(h.z, W3s[(k + 2) * 4 + cc], a);
            a = fmaf(h.w, W3s[(k + 3) * 4 + cc], a);
        }
        outp[((size_t)(bc * 32 + r) * 6 + t) * 4 + cc] = a + br3[t * 4 + cc];
    }
}

// ---------------------------------------------------------------------------
extern "C" void kernel_launch(void* const* d_in, const int* in_sizes, int n_in,
                              void* d_out, int out_size, void* d_ws, size_t ws_size,
                              hipStream_t stream) {
    const float* jets  = (const float*)d_in[0];
    const float* mask  = (const float*)d_in[1];
    const float* tops  = (const float*)d_in[2];
    const float* W_jj1 = (const float*)d_in[3];
    const float* b_jj1 = (const float*)d_in[4];
    const float* W_jj2 = (const float*)d_in[5];
    const float* b_jj2 = (const float*)d_in[6];
    const float* W_jt1 = (const float*)d_in[7];
    const float* b_jt1 = (const float*)d_in[8];
    const float* W_jt2 = (const float*)d_in[9];
    const float* b_jt2 = (const float*)d_in[10];
    const float* W_tj1 = (const float*)d_in[11];
    const float* b_tj1 = (const float*)d_in[12];
    const float* W_tj2 = (const float*)d_in[13];
    const float* b_tj2 = (const float*)d_in[14];
    const float* Wnj1  = (const float*)d_in[15];
    const float* bnj1  = (const float*)d_in[16];
    const float* Wnj2  = (const float*)d_in[17];
    const float* bnj2  = (const float*)d_in[18];
    const float* Wnt1  = (const float*)d_in[19];
    const float* bnt1  = (const float*)d_in[20];
    const float* Wnt2  = (const float*)d_in[21];
    const float* bnt2  = (const float*)d_in[22];
    const float* Wc1   = (const float*)d_in[23];
    const float* bc1   = (const float*)d_in[24];
    const float* Wc2   = (const float*)d_in[25];
    const float* bc2   = (const float*)d_in[26];
    const float* Wc3   = (const float*)d_in[27];
    const float* bc3   = (const float*)d_in[28];
    const float* Wr1   = (const float*)d_in[29];
    const float* br1   = (const float*)d_in[30];
    const float* Wr2   = (const float*)d_in[31];
    const float* br2   = (const float*)d_in[32];
    const float* Wr3   = (const float*)d_in[33];
    const float* br3   = (const float*)d_in[34];

    float* ws = (float*)d_ws;
    constexpr size_t SZ_J = (size_t)1024 * 24 * 128;
    constexpr size_t SZ_T = (size_t)1024 * 6 * 128;
    float* Ajj = ws;
    float* Bjj = Ajj + SZ_J;
    float* Ajt = Bjj + SZ_J;
    float* Btj = Ajt + SZ_J;
    float* Atj = Btj + SZ_J;
    float* Bjt = Atj + SZ_T;
    float* Pjj = Bjt + SZ_T;
    float* Pjt = Pjj + SZ_J;
    float* Ptj = Pjt + SZ_J;
    float* Acc = Ptj + SZ_T;
    float* Bcc = Acc + SZ_T;

    float* outp     = (float*)d_out;
    float* upd_jets = outp;
    float* upd_tops = outp + (size_t)1024 * 24 * 64;
    float* scores   = upd_tops + (size_t)1024 * 6 * 64;
    float* regr     = scores + (size_t)1024 * 6 * 24;

    {   // per-node first-layer pre-activations for the 3 edge MLPs
        PreCfg6 cfg;
        cfg.c[0] = {jets, W_jj1,            b_jj1,  Ajj, 24576};
        cfg.c[1] = {jets, W_jj1 + 64 * 128, nullptr, Bjj, 24576};
        cfg.c[2] = {jets, W_jt1,            b_jt1,  Ajt, 24576};
        cfg.c[3] = {jets, W_tj1 + 64 * 128, nullptr, Btj, 24576};
        cfg.c[4] = {tops, W_tj1,            b_tj1,  Atj, 6144};
        cfg.c[5] = {tops, W_jt1 + 64 * 128, nullptr, Bjt, 6144};
        pre_gemm_kernel<<<dim3(768, 6), 256, 0, stream>>>(cfg);
    }
    edge_mfma_kernel<24, 24, 0, true ><<<1024, 512, 0, stream>>>(
        Ajj, Bjj, W_jj2, b_jj2, mask, nullptr, nullptr, Pjj);
    edge_mfma_kernel<24,  6, 1, false><<<1024, 512, 0, stream>>>(
        Ajt, Bjt, W_jt2, b_jt2, nullptr, nullptr, nullptr, Pjt);
    edge_mfma_kernel< 6, 24, 0, true ><<<1024, 512, 0, stream>>>(
        Atj, Btj, W_tj2, b_tj2, mask, nullptr, nullptr, Ptj);

    node_mlp_kernel<3, true ><<<384, 256, 0, stream>>>(
        SrcSeg{jets, 64}, SrcSeg{Pjj, 128}, SrcSeg{Pjt, 128},
        Wnj1, bnj1, Wnj2, bnj2, mask, upd_jets);
    node_mlp_kernel<2, false><<<96, 256, 0, stream>>>(
        SrcSeg{tops, 64}, SrcSeg{Ptj, 128}, SrcSeg{nullptr, 0},
        Wnt1, bnt1, Wnt2, bnt2, nullptr, upd_tops);

    {   // classifier-edge first layer pre-activations
        PreCfg6 cfg;
        cfg.c[0] = {upd_jets, Wc1 + 64 * 128, nullptr, Bcc, 24576};
        cfg.c[1] = {upd_tops, Wc1,            bc1,     Acc, 6144};
        for (int i = 2; i < 6; ++i) cfg.c[i] = {nullptr, nullptr, nullptr, nullptr, 0};
        pre_gemm_kernel<<<dim3(768, 2), 256, 0, stream>>>(cfg);
    }
    edge_mfma_kernel< 6, 24, 2, true ><<<1024, 512, 0, stream>>>(
        Acc, Bcc, Wc2, bc2, mask, Wc3, bc3, scores);
    reg_kernel<<<dim3(32, 6), 256, 0, stream>>>(upd_tops, Wr1, br1, Wr2, br2, Wr3, br3, regr);
}

// Round 5
// 324.987 us; speedup vs baseline: 2.4345x; 1.3129x over previous
//
#include <hip/hip_runtime.h>
#include <hip/hip_bf16.h>

// TopoGraphBlock on MI355X — round 5 (= round 4 resubmit; GPU timeout, no data).
// Re-audited: LDS union/alignment, swizzle involution, wave-tile cover,
// workspace aliasing order — no defects found.
//
// Round-3 evidence: total 427us; top dispatch node_mlp(jets) ~110us with
// VALUBusy 30%, Occupancy 17%, HBM 2.4% — fp32 latency-bound + grid-starved
// (384 blocks / 256 CUs). This round: both node MLPs in ONE MFMA kernel
// (480 blocks x 512 thr), weights pre-transposed/split to bf16 hi/lo by a
// tiny prep kernel (B-frags become single 16B loads), LDS X-chunk staging
// aliased with swizzled h1 buffer (36.9KB -> 4 blocks/CU).
//
// Split-bf16: A*B ~= Ah*Bh + Al*Bh + Ah*Bl, Al=bf16(A-Ah), rel err ~2^-17.
// MFMA 16x16x32 bf16 layouts (HW-validated rounds 2-3):
//   A: lane holds A[row=lane&15][k=(lane>>4)*8 .. +7]
//   B: lane holds B[k=(lane>>4)*8 .. +7][col=lane&15]
//   D: lane reg j holds D[row=(lane>>4)*4+j][col=lane&15]

#define DEVI __device__ __forceinline__

typedef __attribute__((ext_vector_type(4))) float  floatx4;
typedef __attribute__((ext_vector_type(8))) __bf16 bf16x8;
typedef __attribute__((ext_vector_type(4))) __bf16 bf16x4;

DEVI float4 f4z() { return make_float4(0.f, 0.f, 0.f, 0.f); }
DEVI float4 f4fma(float a, const float4 b, float4 c) {
    c.x = fmaf(a, b.x, c.x); c.y = fmaf(a, b.y, c.y);
    c.z = fmaf(a, b.z, c.z); c.w = fmaf(a, b.w, c.w);
    return c;
}
DEVI float4 f4add(float4 a, const float4 b) {
    a.x += b.x; a.y += b.y; a.z += b.z; a.w += b.w; return a;
}
DEVI float4 f4relu(float4 a) {
    a.x = fmaxf(a.x, 0.f); a.y = fmaxf(a.y, 0.f);
    a.z = fmaxf(a.z, 0.f); a.w = fmaxf(a.w, 0.f);
    return a;
}
DEVI floatx4 mfma_bf16(bf16x8 a, bf16x8 b, floatx4 c) {
    return __builtin_amdgcn_mfma_f32_16x16x32_bf16(a, b, c, 0, 0, 0);
}

// ---------------------------------------------------------------------------
// K0: weight prep — transpose + hi/lo bf16 split.  out[N][K] from src[K][N].
// ---------------------------------------------------------------------------
struct PrepJob { const float* src; __bf16* dh; __bf16* dl; int K; int N; };
struct PrepJobs { PrepJob j[4]; };

__global__ __launch_bounds__(256) void prep_kernel(PrepJobs jobs) {
    const PrepJob jb = jobs.j[blockIdx.y];
    const int n = jb.K * jb.N;
    for (int i = blockIdx.x * 256 + threadIdx.x; i < n; i += gridDim.x * 256) {
        const int c = i / jb.K, k = i - c * jb.K;
        const float w = jb.src[(size_t)k * jb.N + c];
        const __bf16 h = (__bf16)w;
        jb.dh[i] = h;
        jb.dl[i] = (__bf16)(w - (float)h);
    }
}

// ---------------------------------------------------------------------------
// K1: batched per-node first-layer GEMM (fp32). out(nr x 128) = X(nr x 64) @ W(64 x 128)
// ---------------------------------------------------------------------------
struct PreCfg { const float* X; const float* W; const float* bias; float* out; int nrows; };
struct PreCfg6 { PreCfg c[6]; };

__global__ __launch_bounds__(256) void pre_gemm_kernel(PreCfg6 cfgs) {
    const PreCfg cfg = cfgs.c[blockIdx.y];
    if ((int)blockIdx.x * 32 >= cfg.nrows) return;
    __shared__ float Xs[32][64];
    __shared__ float Ws[64][128];
    const int tid = threadIdx.x;
    {
        const float4* s = (const float4*)(cfg.X + (size_t)blockIdx.x * 2048);
        float4* d = (float4*)&Xs[0][0];
        d[tid] = s[tid]; d[tid + 256] = s[tid + 256];
    }
    {
        const float4* s = (const float4*)cfg.W;
        float4* d = (float4*)&Ws[0][0];
        #pragma unroll
        for (int u = 0; u < 8; ++u) d[tid + u * 256] = s[tid + u * 256];
    }
    __syncthreads();
    const int cg = tid & 31, rg = tid >> 5;
    const int c0 = cg * 4, r0 = rg * 4;
    float4 acc[4] = {f4z(), f4z(), f4z(), f4z()};
    #pragma unroll 4
    for (int k = 0; k < 64; k += 4) {
        const float4 w0 = *(const float4*)&Ws[k + 0][c0];
        const float4 w1 = *(const float4*)&Ws[k + 1][c0];
        const float4 w2 = *(const float4*)&Ws[k + 2][c0];
        const float4 w3 = *(const float4*)&Ws[k + 3][c0];
        #pragma unroll
        for (int i = 0; i < 4; ++i) {
            const float4 x = *(const float4*)&Xs[r0 + i][k];
            acc[i] = f4fma(x.x, w0, acc[i]);
            acc[i] = f4fma(x.y, w1, acc[i]);
            acc[i] = f4fma(x.z, w2, acc[i]);
            acc[i] = f4fma(x.w, w3, acc[i]);
        }
    }
    const float4 bv = cfg.bias ? *(const float4*)(cfg.bias + c0) : f4z();
    #pragma unroll
    for (int i = 0; i < 4; ++i)
        *(float4*)&cfg.out[((size_t)blockIdx.x * 32 + r0 + i) * 128 + c0] = f4add(acc[i], bv);
}

// ---------------------------------------------------------------------------
// K2: edge layer-2 GEMM on MFMA, split-bf16, fused pooling epilogue.
// EPI: 0 = register pooling (jj, tj), 1 = LDS segment reduce (jt),
//      2 = classifier score (dot Wc3 + sigmoid * mask).
// ---------------------------------------------------------------------------
template<int NR, int NS, int EPI, bool MASKED>
__global__ __launch_bounds__(512) void edge_mfma_kernel(
    const float* __restrict__ A, const float* __restrict__ Bp,
    const float* __restrict__ W2, const float* __restrict__ b2,
    const float* __restrict__ mask,
    const float* __restrict__ Wc3, const float* __restrict__ bc3,
    float* __restrict__ out)
{
    constexpr int NE    = NR * NS;
    constexpr int NG    = NE / 48;
    constexpr int RPG   = 48 / NS;
    constexpr int PITCH = 136;
    constexpr int OP    = 132;
    constexpr int POUT_SZ = (EPI == 0) ? 4 : 48 * OP;
    constexpr int PART_SZ = (EPI == 2) ? 48 * 9 : 4;

    __shared__ __bf16 HVh[48 * PITCH];
    __shared__ __bf16 HVl[48 * PITCH];
    __shared__ float  msh[32];
    __shared__ float  POUT[POUT_SZ];
    __shared__ float  part[PART_SZ];

    const int b    = blockIdx.x;
    const int tid  = threadIdx.x;
    const int lane = tid & 63;
    const int wave = tid >> 6;
    const int lhi  = lane >> 4;
    const int llo  = lane & 15;
    const int c    = wave * 16 + llo;

    if (tid < 32) msh[tid] = (tid < NS) ? (MASKED ? mask[b * 24 + tid] : 1.f) : 0.f;

    bf16x8 bh[4], bl[4];
    {
        const float* w2c = W2 + c;
        #pragma unroll
        for (int kc = 0; kc < 4; ++kc) {
            #pragma unroll
            for (int j = 0; j < 8; ++j) {
                const float w = w2c[(size_t)(kc * 32 + lhi * 8 + j) * 128];
                const __bf16 h = (__bf16)w;
                bh[kc][j] = h;
                bl[kc][j] = (__bf16)(w - (float)h);
            }
        }
    }
    const float b2c = b2[c];
    __syncthreads();

    float inv = 1.f;
    if constexpr (EPI != 2) {
        if constexpr (MASKED) {
            float sm = 0.f;
            #pragma unroll
            for (int s = 0; s < NS; ++s) sm += msh[s];
            inv = 1.f / fmaxf(sm, 1.f);
        } else {
            inv = 1.f / (float)NS;
        }
    }

    for (int g = 0; g < NG; ++g) {
        #pragma unroll
        for (int it = 0; it < 3; ++it) {
            const int u = tid + it * 512;
            const int e = u >> 5, kq = u & 31;
            const int r = g * RPG + e / NS;
            const int s = e % NS;
            const float4 a4 = *(const float4*)(A  + ((size_t)b * NR + r) * 128 + kq * 4);
            const float4 p4 = *(const float4*)(Bp + ((size_t)b * NS + s) * 128 + kq * 4);
            const float v[4] = {fmaxf(a4.x + p4.x, 0.f), fmaxf(a4.y + p4.y, 0.f),
                                fmaxf(a4.z + p4.z, 0.f), fmaxf(a4.w + p4.w, 0.f)};
            bf16x4 hh, hl;
            #pragma unroll
            for (int q = 0; q < 4; ++q) {
                const __bf16 h = (__bf16)v[q];
                hh[q] = h;
                hl[q] = (__bf16)(v[q] - (float)h);
            }
            *(bf16x4*)&HVh[e * PITCH + kq * 4] = hh;
            *(bf16x4*)&HVl[e * PITCH + kq * 4] = hl;
        }
        __syncthreads();

        floatx4 accs[3];
        #pragma unroll
        for (int mt = 0; mt < 3; ++mt) {
            const int row = mt * 16 + llo;
            bf16x8 ah[4], al[4];
            #pragma unroll
            for (int kc = 0; kc < 4; ++kc) {
                ah[kc] = *(const bf16x8*)&HVh[row * PITCH + kc * 32 + lhi * 8];
                al[kc] = *(const bf16x8*)&HVl[row * PITCH + kc * 32 + lhi * 8];
            }
            floatx4 acc = {0.f, 0.f, 0.f, 0.f};
            #pragma unroll
            for (int kc = 0; kc < 4; ++kc) {
                acc = mfma_bf16(ah[kc], bh[kc], acc);
                acc = mfma_bf16(al[kc], bh[kc], acc);
                acc = mfma_bf16(ah[kc], bl[kc], acc);
            }
            accs[mt] = acc;
        }

        if constexpr (EPI == 0) {
            float p0 = 0.f, p1 = 0.f;
            #pragma unroll
            for (int mt = 0; mt < 3; ++mt) {
                #pragma unroll
                for (int j = 0; j < 4; ++j) {
                    const int el = mt * 16 + lhi * 4 + j;
                    const int s  = (el >= NS) ? el - NS : el;
                    const float v = fmaxf(accs[mt][j] + b2c, 0.f) * msh[s];
                    if (el >= NS) p1 += v; else p0 += v;
                }
            }
            p0 += __shfl_xor(p0, 16); p0 += __shfl_xor(p0, 32);
            p1 += __shfl_xor(p1, 16); p1 += __shfl_xor(p1, 32);
            if (lhi == 0) {
                out[((size_t)b * NR + g * 2 + 0) * 128 + c] = p0 * inv;
                out[((size_t)b * NR + g * 2 + 1) * 128 + c] = p1 * inv;
            }
            __syncthreads();
        } else if constexpr (EPI == 1) {
            #pragma unroll
            for (int mt = 0; mt < 3; ++mt) {
                #pragma unroll
                for (int j = 0; j < 4; ++j) {
                    const int el = mt * 16 + lhi * 4 + j;
                    const int s  = el % NS;
                    POUT[el * OP + c] = fmaxf(accs[mt][j] + b2c, 0.f) * msh[s];
                }
            }
            __syncthreads();
            for (int u = tid; u < RPG * 128; u += 512) {
                const int rl = u >> 7, cc = u & 127;
                float sm2 = 0.f;
                #pragma unroll
                for (int ss = 0; ss < NS; ++ss) sm2 += POUT[(rl * NS + ss) * OP + cc];
                out[((size_t)b * NR + g * RPG + rl) * 128 + cc] = sm2 * inv;
            }
            __syncthreads();
        } else {
            #pragma unroll
            for (int mt = 0; mt < 3; ++mt) {
                #pragma unroll
                for (int j = 0; j < 4; ++j) {
                    const int el = mt * 16 + lhi * 4 + j;
                    POUT[el * OP + c] = fmaxf(accs[mt][j] + b2c, 0.f);
                }
            }
            __syncthreads();
            if (tid < 384) {
                const int e = tid >> 3, cq = tid & 7;
                float sp = 0.f;
                #pragma unroll
                for (int i = 0; i < 16; ++i)
                    sp += POUT[e * OP + cq * 16 + i] * Wc3[cq * 16 + i];
                part[e * 9 + cq] = sp;
            }
            __syncthreads();
            if (tid < 48) {
                float sm2 = 0.f;
                #pragma unroll
                for (int q = 0; q < 8; ++q) sm2 += part[tid * 9 + q];
                const int rr = g * 2 + (tid >= 24 ? 1 : 0);
                const int ss = (tid >= 24) ? tid - 24 : tid;
                out[((size_t)b * NR + rr) * NS + ss] =
                    msh[ss] / (1.f + expf(-(sm2 + bc3[0])));
            }
            __syncthreads();
        }
    }
}

// ---------------------------------------------------------------------------
// K3: both node MLPs on MFMA.  64 rows/block, 512 threads, 8 waves.
// Layer1: K = nch*64 (chunk-staged), N = 128 (wave = col-tile).
// Layer2: K = 128, N = 64 (16 wave-tiles / 8 waves).
// LDS: X chunk (pitch 72) UNION h1 hi/lo (pitch 144, XOR-swizzled 16B blocks).
// Weights come pre-transposed/split as bf16 [N][K] from prep_kernel.
// ---------------------------------------------------------------------------
struct NChunk { const float* base; int stride; };
struct NodeCfg {
    NChunk ch[5]; int nch;
    const __bf16* W1h; const __bf16* W1l; int w1k;
    const float* b1;
    const __bf16* W2h; const __bf16* W2l;
    const float* b2;
    const float* mask;      // per-row (B*NJ) or nullptr
    float* out;
    int nblk;
};

__global__ __launch_bounds__(512) void node_mfma_kernel(NodeCfg c0, NodeCfg c1) {
    constexpr int XP = 72;    // X pitch (bf16), 144B rows: 16B-aligned frags
    constexpr int HP = 144;   // h1 pitch (bf16), 288B rows
    __shared__ char smem[2 * 64 * HP * 2];       // 36864B; X region aliases
    __bf16* Xh  = (__bf16*)smem;                 // [64][72]
    __bf16* Xl  = Xh + 64 * XP;
    __bf16* H1h = (__bf16*)smem;                 // [64][144] (aliases X)
    __bf16* H1l = H1h + 64 * HP;

    const bool first = (int)blockIdx.x < c0.nblk;
    const NodeCfg& cfg = first ? c0 : c1;
    const int rb  = first ? blockIdx.x : blockIdx.x - c0.nblk;
    const int row0 = rb * 64;

    const int tid  = threadIdx.x;
    const int lane = tid & 63;
    const int wave = tid >> 6;
    const int lhi  = lane >> 4;
    const int llo  = lane & 15;
    const int c    = wave * 16 + llo;            // layer-1 col 0..127

    // ---- layer 1: acc[mt] over nch chunks of K=64 ----
    floatx4 acc[4] = {{0,0,0,0},{0,0,0,0},{0,0,0,0},{0,0,0,0}};
    for (int ch = 0; ch < cfg.nch; ++ch) {
        const NChunk cc = cfg.ch[ch];
        #pragma unroll
        for (int it = 0; it < 2; ++it) {
            const int u = tid + it * 512;
            const int r = u >> 4, kq = u & 15;
            const float4 x4 = *(const float4*)(cc.base + (size_t)(row0 + r) * cc.stride + kq * 4);
            const float v[4] = {x4.x, x4.y, x4.z, x4.w};
            bf16x4 hh, hl;
            #pragma unroll
            for (int q = 0; q < 4; ++q) {
                const __bf16 h = (__bf16)v[q];
                hh[q] = h;
                hl[q] = (__bf16)(v[q] - (float)h);
            }
            *(bf16x4*)&Xh[r * XP + kq * 4] = hh;
            *(bf16x4*)&Xl[r * XP + kq * 4] = hl;
        }
        __syncthreads();
        #pragma unroll
        for (int ks = 0; ks < 2; ++ks) {
            const int kg = ch * 64 + ks * 32 + lhi * 8;
            const bf16x8 bh = *(const bf16x8*)&cfg.W1h[(size_t)c * cfg.w1k + kg];
            const bf16x8 bl = *(const bf16x8*)&cfg.W1l[(size_t)c * cfg.w1k + kg];
            #pragma unroll
            for (int mt = 0; mt < 4; ++mt) {
                const int ro = (mt * 16 + llo) * XP + ks * 32 + lhi * 8;
                const bf16x8 ah = *(const bf16x8*)&Xh[ro];
                const bf16x8 al = *(const bf16x8*)&Xl[ro];
                acc[mt] = mfma_bf16(ah, bh, acc[mt]);
                acc[mt] = mfma_bf16(al, bh, acc[mt]);
                acc[mt] = mfma_bf16(ah, bl, acc[mt]);
            }
        }
        __syncthreads();   // X dead -> safe to overwrite (next chunk or h1)
    }

    // ---- h1 = relu(acc + b1) -> swizzled hi/lo LDS ----
    {
        const float b1c = cfg.b1[c];
        #pragma unroll
        for (int mt = 0; mt < 4; ++mt) {
            #pragma unroll
            for (int j = 0; j < 4; ++j) {
                const int row = mt * 16 + lhi * 4 + j;
                const float v = fmaxf(acc[mt][j] + b1c, 0.f);
                const __bf16 h = (__bf16)v;
                const int blk = (c >> 3) ^ (row & 7);
                const int off = row * HP + blk * 8 + (c & 7);
                H1h[off] = h;
                H1l[off] = (__bf16)(v - (float)h);
            }
        }
    }
    __syncthreads();

    // ---- layer 2: K=128, N=64; wave w -> col-tile w&3, M-tiles {w>>2, (w>>2)+2}
    const int ct2 = wave & 3;
    const int c2  = ct2 * 16 + llo;
    const int mtb = wave >> 2;
    floatx4 acc2[2] = {{0,0,0,0},{0,0,0,0}};
    #pragma unroll
    for (int ks = 0; ks < 4; ++ks) {
        const int kg = ks * 32 + lhi * 8;
        const bf16x8 bh = *(const bf16x8*)&cfg.W2h[(size_t)c2 * 128 + kg];
        const bf16x8 bl = *(const bf16x8*)&cfg.W2l[(size_t)c2 * 128 + kg];
        #pragma unroll
        for (int i = 0; i < 2; ++i) {
            const int row = (mtb + i * 2) * 16 + llo;
            const int blk = (ks * 4 + lhi) ^ (row & 7);
            const bf16x8 ah = *(const bf16x8*)&H1h[row * HP + blk * 8];
            const bf16x8 al = *(const bf16x8*)&H1l[row * HP + blk * 8];
            acc2[i] = mfma_bf16(ah, bh, acc2[i]);
            acc2[i] = mfma_bf16(al, bh, acc2[i]);
            acc2[i] = mfma_bf16(ah, bl, acc2[i]);
        }
    }
    {
        const float b2c = cfg.b2[c2];
        #pragma unroll
        for (int i = 0; i < 2; ++i) {
            #pragma unroll
            for (int j = 0; j < 4; ++j) {
                const int row = (mtb + i * 2) * 16 + lhi * 4 + j;
                float v = fmaxf(acc2[i][j] + b2c, 0.f);
                if (cfg.mask) v *= cfg.mask[row0 + row];
                cfg.out[(size_t)(row0 + row) * 64 + c2] = v;
            }
        }
    }
}

// ---------------------------------------------------------------------------
// K6: per-top regression head (fp32): 64 -> 128 -> 128 -> 4, per-t weights.
// ---------------------------------------------------------------------------
__global__ __launch_bounds__(256) void reg_kernel(
    const float* __restrict__ tops_upd,
    const float* __restrict__ Wr1, const float* __restrict__ br1,
    const float* __restrict__ Wr2, const float* __restrict__ br2,
    const float* __restrict__ Wr3, const float* __restrict__ br3,
    float* __restrict__ outp) {
    const int t = blockIdx.y, bc = blockIdx.x, tid = threadIdx.x;
    __shared__ float Xs[32][64];
    __shared__ float h1[32][128];
    __shared__ float h2[32][132];
    __shared__ float W3s[512];
    for (int u = tid; u < 512; u += 256) {
        const int r = u >> 4, k4 = (u & 15) * 4;
        *(float4*)&Xs[r][k4] =
            *(const float4*)(tops_upd + ((size_t)(bc * 32 + r) * 6 + t) * 64 + k4);
    }
    for (int u = tid; u < 512; u += 256) W3s[u] = Wr3[t * 512 + u];
    __syncthreads();

    const int cg = tid & 31, rg = tid >> 5;
    const int c0 = cg * 4, r0 = rg * 4;
    const float* W1 = Wr1 + (size_t)t * 64 * 128;
    float4 acc[4];
    #pragma unroll
    for (int i = 0; i < 4; ++i) acc[i] = f4z();
    #pragma unroll 4
    for (int k = 0; k < 64; k += 4) {
        const float4 w0 = *(const float4*)(W1 + (size_t)(k + 0) * 128 + c0);
        const float4 w1 = *(const float4*)(W1 + (size_t)(k + 1) * 128 + c0);
        const float4 w2 = *(const float4*)(W1 + (size_t)(k + 2) * 128 + c0);
        const float4 w3 = *(const float4*)(W1 + (size_t)(k + 3) * 128 + c0);
        #pragma unroll
        for (int i = 0; i < 4; ++i) {
            const float4 x = *(const float4*)&Xs[r0 + i][k];
            acc[i] = f4fma(x.x, w0, acc[i]);
            acc[i] = f4fma(x.y, w1, acc[i]);
            acc[i] = f4fma(x.z, w2, acc[i]);
            acc[i] = f4fma(x.w, w3, acc[i]);
        }
    }
    const float4 b1v = *(const float4*)(br1 + t * 128 + c0);
    #pragma unroll
    for (int i = 0; i < 4; ++i)
        *(float4*)&h1[r0 + i][c0] = f4relu(f4add(acc[i], b1v));
    __syncthreads();

    const float* W2 = Wr2 + (size_t)t * 128 * 128;
    #pragma unroll
    for (int i = 0; i < 4; ++i) acc[i] = f4z();
    #pragma unroll 4
    for (int k = 0; k < 128; k += 4) {
        const float4 w0 = *(const float4*)(W2 + (size_t)(k + 0) * 128 + c0);
        const float4 w1 = *(const float4*)(W2 + (size_t)(k + 1) * 128 + c0);
        const float4 w2 = *(const float4*)(W2 + (size_t)(k + 2) * 128 + c0);
        const float4 w3 = *(const float4*)(W2 + (size_t)(k + 3) * 128 + c0);
        #pragma unroll
        for (int i = 0; i < 4; ++i) {
            const float4 h = *(const float4*)&h1[r0 + i][k];
            acc[i] = f4fma(h.x, w0, acc[i]);
            acc[i] = f4fma(h.y, w1, acc[i]);
            acc[i] = f4fma(h.z, w2, acc[i]);
            acc[i] = f4fma(h.w, w3, acc[i]);
        }
    }
    const float4 b2v = *(const float4*)(br2 + t * 128 + c0);
    #pragma unroll
    for (int i = 0; i < 4; ++i)
        *(float4*)&h2[r0 + i][c0] = f4relu(f4add(acc[i], b2v));
    __syncthreads();

    if (tid < 128) {
        const int r = tid >> 2, cc = tid & 3;
        float a = 0.f;
        #pragma unroll 4
        for (int k = 0; k < 128; k += 4) {
            const float4 h = *(const float4*)&h2[r][k];
            a = fmaf(h.x, W3s[(k + 0) * 4 + cc], a);
            a = fmaf(h.y, W3s[(k + 1) * 4 + cc], a);
            a = fmaf(h.z, W3s[(k + 2) * 4 + cc], a);
            a = fmaf(h.w, W3s[(k + 3) * 4 + cc], a);
        }
        outp[((size_t)(bc * 32 + r) * 6 + t) * 4 + cc] = a + br3[t * 4 + cc];
    }
}

// ---------------------------------------------------------------------------
extern "C" void kernel_launch(void* const* d_in, const int* in_sizes, int n_in,
                              void* d_out, int out_size, void* d_ws, size_t ws_size,
                              hipStream_t stream) {
    const float* jets  = (const float*)d_in[0];
    const float* mask  = (const float*)d_in[1];
    const float* tops  = (const float*)d_in[2];
    const float* W_jj1 = (const float*)d_in[3];
    const float* b_jj1 = (const float*)d_in[4];
    const float* W_jj2 = (const float*)d_in[5];
    const float* b_jj2 = (const float*)d_in[6];
    const float* W_jt1 = (const float*)d_in[7];
    const float* b_jt1 = (const float*)d_in[8];
    const float* W_jt2 = (const float*)d_in[9];
    const float* b_jt2 = (const float*)d_in[10];
    const float* W_tj1 = (const float*)d_in[11];
    const float* b_tj1 = (const float*)d_in[12];
    const float* W_tj2 = (const float*)d_in[13];
    const float* b_tj2 = (const float*)d_in[14];
    const float* Wnj1  = (const float*)d_in[15];
    const float* bnj1  = (const float*)d_in[16];
    const float* Wnj2  = (const float*)d_in[17];
    const float* bnj2  = (const float*)d_in[18];
    const float* Wnt1  = (const float*)d_in[19];
    const float* bnt1  = (const float*)d_in[20];
    const float* Wnt2  = (const float*)d_in[21];
    const float* bnt2  = (const float*)d_in[22];
    const float* Wc1   = (const float*)d_in[23];
    const float* bc1   = (const float*)d_in[24];
    const float* Wc2   = (const float*)d_in[25];
    const float* bc2   = (const float*)d_in[26];
    const float* Wc3   = (const float*)d_in[27];
    const float* bc3   = (const float*)d_in[28];
    const float* Wr1   = (const float*)d_in[29];
    const float* br1   = (const float*)d_in[30];
    const float* Wr2   = (const float*)d_in[31];
    const float* br2   = (const float*)d_in[32];
    const float* Wr3   = (const float*)d_in[33];
    const float* br3   = (const float*)d_in[34];

    float* ws = (float*)d_ws;
    constexpr size_t SZ_J = (size_t)1024 * 24 * 128;
    constexpr size_t SZ_T = (size_t)1024 * 6 * 128;
    float* Ajj = ws;
    float* Bjj = Ajj + SZ_J;
    float* Ajt = Bjj + SZ_J;
    float* Btj = Ajt + SZ_J;
    float* Atj = Btj + SZ_J;
    float* Bjt = Atj + SZ_T;
    float* Pjj = Bjt + SZ_T;
    float* Pjt = Pjj + SZ_J;
    float* Ptj = Pjt + SZ_J;
    float* Acc = Ptj + SZ_T;
    float* Bcc = Acc + SZ_T;

    // bf16 split-weight arrays alias the Acc region: Acc is written by the
    // cls pre_gemm only AFTER node_mfma has consumed these. 320KB << 3MB.
    __bf16* W1njT_h = (__bf16*)Acc;
    __bf16* W1njT_l = W1njT_h + 320 * 128;
    __bf16* W2njT_h = W1njT_l + 320 * 128;
    __bf16* W2njT_l = W2njT_h + 128 * 64;
    __bf16* W1ntT_h = W2njT_l + 128 * 64;
    __bf16* W1ntT_l = W1ntT_h + 192 * 128;
    __bf16* W2ntT_h = W1ntT_l + 192 * 128;
    __bf16* W2ntT_l = W2ntT_h + 128 * 64;

    float* outp     = (float*)d_out;
    float* upd_jets = outp;
    float* upd_tops = outp + (size_t)1024 * 24 * 64;
    float* scores   = upd_tops + (size_t)1024 * 6 * 64;
    float* regr     = scores + (size_t)1024 * 6 * 24;

    {   // weight prep (transpose + hi/lo split) for node MLPs
        PrepJobs pj;
        pj.j[0] = {Wnj1, W1njT_h, W1njT_l, 320, 128};
        pj.j[1] = {Wnj2, W2njT_h, W2njT_l, 128, 64};
        pj.j[2] = {Wnt1, W1ntT_h, W1ntT_l, 192, 128};
        pj.j[3] = {Wnt2, W2ntT_h, W2ntT_l, 128, 64};
        prep_kernel<<<dim3(160, 4), 256, 0, stream>>>(pj);
    }
    {   // per-node first-layer pre-activations for the 3 edge MLPs
        PreCfg6 cfg;
        cfg.c[0] = {jets, W_jj1,            b_jj1,  Ajj, 24576};
        cfg.c[1] = {jets, W_jj1 + 64 * 128, nullptr, Bjj, 24576};
        cfg.c[2] = {jets, W_jt1,            b_jt1,  Ajt, 24576};
        cfg.c[3] = {jets, W_tj1 + 64 * 128, nullptr, Btj, 24576};
        cfg.c[4] = {tops, W_tj1,            b_tj1,  Atj, 6144};
        cfg.c[5] = {tops, W_jt1 + 64 * 128, nullptr, Bjt, 6144};
        pre_gemm_kernel<<<dim3(768, 6), 256, 0, stream>>>(cfg);
    }
    edge_mfma_kernel<24, 24, 0, true ><<<1024, 512, 0, stream>>>(
        Ajj, Bjj, W_jj2, b_jj2, mask, nullptr, nullptr, Pjj);
    edge_mfma_kernel<24,  6, 1, false><<<1024, 512, 0, stream>>>(
        Ajt, Bjt, W_jt2, b_jt2, nullptr, nullptr, nullptr, Pjt);
    edge_mfma_kernel< 6, 24, 0, true ><<<1024, 512, 0, stream>>>(
        Atj, Btj, W_tj2, b_tj2, mask, nullptr, nullptr, Ptj);

    {   // both node MLPs, one launch
        NodeCfg cj, ct;
        cj.ch[0] = {jets, 64};
        cj.ch[1] = {Pjj, 128};      cj.ch[2] = {Pjj + 64, 128};
        cj.ch[3] = {Pjt, 128};      cj.ch[4] = {Pjt + 64, 128};
        cj.nch = 5;
        cj.W1h = W1njT_h; cj.W1l = W1njT_l; cj.w1k = 320; cj.b1 = bnj1;
        cj.W2h = W2njT_h; cj.W2l = W2njT_l; cj.b2 = bnj2;
        cj.mask = mask; cj.out = upd_jets; cj.nblk = 384;

        ct.ch[0] = {tops, 64};
        ct.ch[1] = {Ptj, 128};      ct.ch[2] = {Ptj + 64, 128};
        ct.ch[3] = {nullptr, 0};    ct.ch[4] = {nullptr, 0};
        ct.nch = 3;
        ct.W1h = W1ntT_h; ct.W1l = W1ntT_l; ct.w1k = 192; ct.b1 = bnt1;
        ct.W2h = W2ntT_h; ct.W2l = W2ntT_l; ct.b2 = bnt2;
        ct.mask = nullptr; ct.out = upd_tops; ct.nblk = 96;

        node_mfma_kernel<<<480, 512, 0, stream>>>(cj, ct);
    }

    {   // classifier-edge first layer pre-activations (overwrites Acc region)
        PreCfg6 cfg;
        cfg.c[0] = {upd_jets, Wc1 + 64 * 128, nullptr, Bcc, 24576};
        cfg.c[1] = {upd_tops, Wc1,            bc1,     Acc, 6144};
        for (int i = 2; i < 6; ++i) cfg.c[i] = {nullptr, nullptr, nullptr, nullptr, 0};
        pre_gemm_kernel<<<dim3(768, 2), 256, 0, stream>>>(cfg);
    }
    edge_mfma_kernel< 6, 24, 2, true ><<<1024, 512, 0, stream>>>(
        Acc, Bcc, Wc2, bc2, mask, Wc3, bc3, scores);
    reg_kernel<<<dim3(32, 6), 256, 0, stream>>>(upd_tops, Wr1, br1, Wr2, br2, Wr3, br3, regr);
}